// Round 1
// baseline (333.664 us; speedup 1.0000x reference)
//
#include <hip/hip_runtime.h>

// NRI edge-MLP encoder, fused single kernel (NO workspace):
// out[b,e,:] = relu(concat(x[b,send(e)], x[b,recv(e)]) @ W1^T + b1) @ W2^T + b2
// B=8, N=256, E=65280, n_in=64, n_hid=128, n_out=64.
// edge e: recv = e/255, k = e%255, send = k + (k >= recv)
//
// Round-0 theory: the previous 2-kernel version staged bf16 x/W1/W2 into d_ws.
// rocprof top-5 is entirely fillBufferAligned dispatches (~80us each) writing
// 522240 KB = 4x out size -- workspace poison fills, not our kernels (nri_mlp
// absent from top-5 => <78us; write roofline for the 134MB output is ~21us).
// This version converts fp32->bf16 on the fly and never touches d_ws, so the
// ws poison has nothing to protect. MFMA structure / LDS swizzle / store path
// are identical to the verified kernel: the explicit swizzled ds_write below
// reproduces exactly the lane->LDS mapping global_load_lds produced.

using frag_t  = __attribute__((ext_vector_type(8))) short;          // 8 bf16 = 4 VGPRs
using f32x4   = __attribute__((ext_vector_type(4))) float;
using ushort8 = __attribute__((ext_vector_type(8))) unsigned short;

__device__ inline unsigned short f2bf(float f) {
    union { float f; unsigned u; } v; v.f = f;
    unsigned r = v.u + 0x7fffu + ((v.u >> 16) & 1u);   // RTNE
    return (unsigned short)(r >> 16);
}

__device__ inline ushort8 cvt8(const float* __restrict__ s) {
    f32x4 a = *(const f32x4*)s;
    f32x4 b = *(const f32x4*)(s + 4);
    ushort8 o;
    o[0] = f2bf(a[0]); o[1] = f2bf(a[1]); o[2] = f2bf(a[2]); o[3] = f2bf(a[3]);
    o[4] = f2bf(b[0]); o[5] = f2bf(b[1]); o[6] = f2bf(b[2]); o[7] = f2bf(b[3]);
    return o;
}

__device__ inline frag_t cvt_frag(const float* __restrict__ s) {
    union { ushort8 u; frag_t f; } v;
    v.u = cvt8(s);
    return v.f;
}

// grid 2040 = 8 batches x 255 blocks x 256 edges. Wave owns 64 edges, no barriers
// (each wave's LDS slab is private; plain C++ ds_write->ds_read ordering is
// handled by the compiler's lgkmcnt insertion).
// LDS: per-wave 16 KB A/H buffer, row-major 128-elem rows, 16B chunks XOR-swizzled
// (slot = chunk ^ (row&7)) for conflict-free ds_read_b128 fragments. W1/W2
// fragments are loaded fp32 from global (L2-resident broadcast) and converted
// in-register, reused over 4 tiles. Layer2 computes out^T = W2 @ H^T -> C rows =
// 4 consecutive out-features -> direct float4 stores.
__global__ __launch_bounds__(256, 2) void nri_mlp_fused(const float* __restrict__ x,
                                                        const float* __restrict__ W1,
                                                        const float* __restrict__ b1,
                                                        const float* __restrict__ W2,
                                                        const float* __restrict__ b2,
                                                        float* __restrict__ out) {
    __shared__ unsigned short Sh[4][64 * 128];   // 64 KB: 4 waves x (64 edges x 128)

    const int tid  = threadIdx.x;
    const int wave = tid >> 6;
    const int lane = tid & 63;
    const int quad = lane >> 4;
    const int n16  = lane & 15;

    const int bx = blockIdx.x;
    const int b  = bx / 255;
    const int eb = (bx - b * 255) * 256;
    const int e0 = eb + wave * 64;               // this wave's 64 edges

    const float* xb = x + b * (256 * 64);
    unsigned short* Aw = &Sh[wave][0];

    // ---- stage A: fp32 gather -> bf16 -> swizzled LDS. Same layout as before:
    // lane l handles row i*4 + l/16, slot l%16; slot holds data chunk slot^(row&7).
    {
        const int r4   = lane >> 4;      // 0..3
        const int slot = lane & 15;
        #pragma unroll
        for (int i = 0; i < 16; ++i) {
            int rr   = i * 4 + r4;                       // local edge row 0..63
            int e    = e0 + rr;
            int recv = e / 255;
            int kk   = e - recv * 255;
            int send = kk + (kk >= recv ? 1 : 0);
            int c    = slot ^ (rr & 7);                  // data chunk stored at this slot
            int node = (c < 8) ? send : recv;
            const float* src = xb + node * 64 + (c & 7) * 8;   // 32B-aligned
            *(ushort8*)&Aw[rr * 128 + slot * 8] = cvt8(src);
        }
    }

    // ---- W1 fragments -> registers (B-operand: lane n16 = W1 row, k-run), fp32->bf16 ----
    frag_t w1f[4][8];
    #pragma unroll
    for (int ks = 0; ks < 4; ++ks)
        #pragma unroll
        for (int c = 0; c < 8; ++c)
            w1f[ks][c] = cvt_frag(W1 + (c * 16 + n16) * 128 + ks * 32 + quad * 8);

    float b1v[8];
    #pragma unroll
    for (int c = 0; c < 8; ++c) b1v[c] = b1[c * 16 + n16];

    // ---- phase 1: H = relu(A @ W1^T + b1), tile-by-tile, H overwrites A rows ----
    #pragma unroll
    for (int t = 0; t < 4; ++t) {
        frag_t af[4];
        #pragma unroll
        for (int ks = 0; ks < 4; ++ks) {
            int r    = t * 16 + n16;
            int slot = (ks * 4 + quad) ^ (r & 7);
            af[ks] = *(const frag_t*)&Aw[r * 128 + slot * 8];
        }
        f32x4 acc[8];
        #pragma unroll
        for (int c = 0; c < 8; ++c) acc[c] = (f32x4){0.f, 0.f, 0.f, 0.f};
        #pragma unroll
        for (int ks = 0; ks < 4; ++ks)
            #pragma unroll
            for (int c = 0; c < 8; ++c)
                acc[c] = __builtin_amdgcn_mfma_f32_16x16x32_bf16(af[ks], w1f[ks][c], acc[c], 0, 0, 0);

        // C-layout: col = n16 (hid feat c*16+n16), row = quad*4+r_i (edge row)
        #pragma unroll
        for (int c = 0; c < 8; ++c) {
            float bv = b1v[c];
            #pragma unroll
            for (int ri = 0; ri < 4; ++ri) {
                float v = acc[c][ri] + bv;
                v = v > 0.f ? v : 0.f;
                int row  = t * 16 + quad * 4 + ri;
                int k    = c * 16 + n16;
                int slot = (k >> 3) ^ (row & 7);
                Aw[row * 128 + slot * 8 + (n16 & 7)] = f2bf(v);
            }
        }
    }

    // ---- phase 2: out^T = W2 @ H^T. A-operand = W2 rows, B-operand = H rows ----
    frag_t w2f[4][4];
    #pragma unroll
    for (int ks = 0; ks < 4; ++ks)
        #pragma unroll
        for (int c2 = 0; c2 < 4; ++c2)
            w2f[ks][c2] = cvt_frag(W2 + (c2 * 16 + n16) * 128 + ks * 32 + quad * 8);

    float b2v[4][4];
    #pragma unroll
    for (int c2 = 0; c2 < 4; ++c2)
        #pragma unroll
        for (int ri = 0; ri < 4; ++ri)
            b2v[c2][ri] = b2[c2 * 16 + quad * 4 + ri];

    #pragma unroll
    for (int t = 0; t < 4; ++t) {
        frag_t hf[4];
        #pragma unroll
        for (int ks = 0; ks < 4; ++ks) {
            int r    = t * 16 + n16;
            int slot = (ks * 4 + quad) ^ (r & 7);
            hf[ks] = *(const frag_t*)&Aw[r * 128 + slot * 8];
        }
        f32x4 acc2[4];
        #pragma unroll
        for (int c2 = 0; c2 < 4; ++c2) acc2[c2] = (f32x4){0.f, 0.f, 0.f, 0.f};
        #pragma unroll
        for (int ks = 0; ks < 4; ++ks)
            #pragma unroll
            for (int c2 = 0; c2 < 4; ++c2)
                acc2[c2] = __builtin_amdgcn_mfma_f32_16x16x32_bf16(w2f[ks][c2], hf[ks], acc2[c2], 0, 0, 0);

        // C-layout: col = n16 = edge, row = quad*4+reg = out-feature -> float4 store
        float* ob = out + ((long)b * 65280 + e0 + t * 16 + n16) * 64;
        #pragma unroll
        for (int c2 = 0; c2 < 4; ++c2) {
            f32x4 v;
            #pragma unroll
            for (int ri = 0; ri < 4; ++ri) v[ri] = acc2[c2][ri] + b2v[c2][ri];
            *(f32x4*)&ob[c2 * 16 + quad * 4] = v;
        }
    }
}

extern "C" void kernel_launch(void* const* d_in, const int* in_sizes, int n_in,
                              void* d_out, int out_size, void* d_ws, size_t ws_size,
                              hipStream_t stream) {
    const float* x  = (const float*)d_in[0];
    // d_in[1] = rel_rec, d_in[2] = rel_send: one-hot incidence, replaced by index math
    const float* W1 = (const float*)d_in[3];
    const float* b1 = (const float*)d_in[4];
    const float* W2 = (const float*)d_in[5];
    const float* b2 = (const float*)d_in[6];
    (void)d_ws; (void)ws_size;   // workspace intentionally untouched
    float* out = (float*)d_out;

    nri_mlp_fused<<<2040, 256, 0, stream>>>(x, W1, b1, W2, b2, out);
}